// Round 4
// baseline (73.954 us; speedup 1.0000x reference)
//
#include <hip/hip_runtime.h>

// Problem constants (match reference)
#define B_  8
#define L_  512
#define C_  6
#define N_  (B_ * L_)
#define K_  9
#define BIGF 1e10f

// Output layout (flat float32, concatenated in return order)
#define NK        (N_ * K_)               // 36864
#define OFF_DKNN  0
#define OFF_SRC   (NK)
#define OFF_DST   (2 * NK)
#define OFF_VALID (3 * NK)
#define OFF_GLB   (4 * NK)
#define GLB_PER   (2 * L_ - 1)            // 1023
#define GLB_TOT   (2 * B_ * GLB_PER)      // 16368
#define OFF_SEQ   (OFF_GLB + GLB_TOT)
#define SEQ_PER   (2 * (L_ - 2))          // 1020
#define SEQ_TOT   (2 * B_ * SEQ_PER)      // 16320

#define TPB 512            // 8 waves = 8 rows per block
#define RPB 8

typedef float v2f __attribute__((ext_vector_type(2)));

static __device__ __forceinline__ unsigned umin32(unsigned a, unsigned b) {
    return a < b ? a : b;
}

// Block = one 8-row slice of a graph. Preps the graph's 512 nodes into LDS in
// channel-PAIR layout so the distance loop runs on packed fp32 (v_pk_fma_f32):
//   A[p][col] = (x_{2p}, x_{2p+1}, y_{2p}, y_{2p+1})
//   Bq[p][col] = (z_{2p}, z_{2p+1}, sq_{2p}+mask, sq_{2p+1}+mask)
// Each of the 8 waves computes one row's 512 distances and selects top-9
// in-wave on 32-bit quantized keys (23-bit d2 prefix | 9-bit col).
__global__ __launch_bounds__(TPB, 4) void fused_kernel(const float* __restrict__ X,
                                                       const int* __restrict__ AP,
                                                       const int* __restrict__ S,
                                                       const int* __restrict__ sec,
                                                       float* __restrict__ out) {
    __shared__ float4 A[3][L_];    // 24 KB
    __shared__ float4 Bq[3][L_];   // 24 KB

    const int tid = threadIdx.x;
    const int lane = tid & 63;
    const int wv = tid >> 6;
    const int row = blockIdx.x * RPB + wv;
    const int base = row & ~(L_ - 1);
    const int rl = row & (L_ - 1);

    // ---- static glb/seq edge lists (first 32 blocks' threads) ----
    {
        const int gt = blockIdx.x * TPB + tid;
        if (gt < GLB_TOT) {
            const int r = gt / (B_ * GLB_PER);
            const int rem = gt % (B_ * GLB_PER);
            const int b = rem / GLB_PER;
            const int q = rem % GLB_PER;
            int v;
            if (r == 0) v = (q < L_) ? 0 : (q - (L_ - 1));   // src: [0]*L ++ [1..L-1]
            else        v = (q < L_) ? q : 0;                // dst: [0..L-1] ++ [0]*(L-1)
            out[OFF_GLB + gt] = (float)(v + b * L_);
        }
        if (gt < SEQ_TOT) {
            const int r = gt / (B_ * SEQ_PER);
            const int rem = gt % (B_ * SEQ_PER);
            const int b = rem / SEQ_PER;
            const int q = rem % SEQ_PER;
            int v;
            if (r == 0) v = (q < L_ - 2) ? (q + 1) : (q - (L_ - 2) + 2);  // [1..510]++[2..511]
            else        v = (q < L_ - 2) ? (q + 2) : (q - (L_ - 2) + 1);  // [2..511]++[1..510]
            out[OFF_SEQ + gt] = (float)(v + b * L_);
        }
    }

    // ---- prep: thread t packs node (base+t) into pair-layout LDS ----
    {
        const int node = base + tid;
        const float* x = X + (size_t)node * (C_ * 3);
        const float bias_g = (S[node] == 0) ? BIGF : 0.0f;
#pragma unroll
        for (int p = 0; p < 3; ++p) {
            const int c0 = 2 * p, c1 = 2 * p + 1;
            const float x0 = x[c0 * 3], y0 = x[c0 * 3 + 1], z0 = x[c0 * 3 + 2];
            const float x1 = x[c1 * 3], y1 = x[c1 * 3 + 1], z1 = x[c1 * 3 + 2];
            float sq0 = (x0 * x0 + y0 * y0) + z0 * z0;
            float sq1 = (x1 * x1 + y1 * y1) + z1 * z1;
            if (AP[node * C_ + c0] == 0) sq0 += BIGF;  // padded channel loses every min
            if (AP[node * C_ + c1] == 0) sq1 += BIGF;
            A[p][tid]  = make_float4(x0, x1, y0, y1);
            Bq[p][tid] = make_float4(z0, z1, sq0 + bias_g, sq1 + bias_g);
        }
    }
    __syncthreads();

    // ---- row fragment: splat own record into v2f regs, fold -2 into coords ----
    v2f ax2[C_], ay2[C_], az2[C_], sc2[C_];
#pragma unroll
    for (int p = 0; p < 3; ++p) {
        const float4 va = A[p][rl];
        const float4 vb = Bq[p][rl];
        ax2[2 * p]     = (v2f)(-2.0f * va.x);
        ax2[2 * p + 1] = (v2f)(-2.0f * va.y);
        ay2[2 * p]     = (v2f)(-2.0f * va.z);
        ay2[2 * p + 1] = (v2f)(-2.0f * va.w);
        az2[2 * p]     = (v2f)(-2.0f * vb.x);
        az2[2 * p + 1] = (v2f)(-2.0f * vb.y);
        sc2[2 * p]     = (v2f)(vb.z);
        sc2[2 * p + 1] = (v2f)(vb.w);
    }

    // ---- distances: lane j owns cols {j, 64+j, ..., 448+j} ----
    unsigned v[8];
#pragma unroll
    for (int s = 0; s < 8; ++s) {
        const int col = s * 64 + lane;
        float m = 3.0e38f;
#pragma unroll
        for (int p = 0; p < 3; ++p) {
            const float4 va = A[p][col];
            const float4 vb = Bq[p][col];
            const v2f xs = {va.x, va.y};
            const v2f ys = {va.z, va.w};
            const v2f zs = {vb.x, vb.y};
            const v2f sqs = {vb.z, vb.w};
            v2f md = (v2f)(3.0e38f);
#pragma unroll
            for (int c = 0; c < C_; ++c) {
                v2f t = __builtin_elementwise_fma(ax2[c], xs, sc2[c]);
                t = __builtin_elementwise_fma(ay2[c], ys, t);
                t = __builtin_elementwise_fma(az2[c], zs, t);
                md = __builtin_elementwise_min(md, t);
            }
            const v2f ms = md + sqs;
            m = fminf(m, fminf(ms.x, ms.y));
        }
        m = fmaxf(m, 0.0f);   // d2; masked pairs land >= ~1e10
        // 23-bit value prefix + 9-bit col: u32 order == (d2, col) lexicographic
        v[s] = (__float_as_uint(m) & 0xFFFFFE00u) | (unsigned)col;
    }

    // ---- 9 rounds of stable wave argmin on u32 keys ----
    unsigned mine = 0xFFFFFFFFu;
#pragma unroll
    for (int t = 0; t < K_; ++t) {
        unsigned loc = v[0];
#pragma unroll
        for (int s = 1; s < 8; ++s) loc = umin32(loc, v[s]);
#pragma unroll
        for (int off = 32; off >= 1; off >>= 1) {
            const unsigned o = (unsigned)__shfl_xor((int)loc, off, 64);
            loc = umin32(loc, o);
        }
        if (lane == t) mine = loc;                 // lane t keeps round-t winner
#pragma unroll
        for (int s = 0; s < 8; ++s)                // remove winner (keys unique)
            v[s] = (v[s] == loc) ? 0xFFFFFFFFu : v[s];
    }

    // ---- epilogue: lanes 0..8 write the 4 per-edge outputs ----
    if (lane < K_) {
        const int col = (int)(mine & 511u);
        const float d2 = __uint_as_float(mine & 0xFFFFFE00u);
        const bool masked = (d2 >= 1.0e9f);        // valid pairs are < ~1e5
        const float dval = masked ? BIGF : sqrtf(d2);
        const int dst = base + col;
        const bool valid = !masked && (sec[row] == sec[dst]);
        const size_t o = (size_t)row * K_ + lane;
        out[OFF_DKNN + o]  = dval;
        out[OFF_SRC + o]   = (float)row;
        out[OFF_DST + o]   = valid ? (float)dst : -1.0f;
        out[OFF_VALID + o] = valid ? 1.0f : 0.0f;
    }
}

extern "C" void kernel_launch(void* const* d_in, const int* in_sizes, int n_in,
                              void* d_out, int out_size, void* d_ws, size_t ws_size,
                              hipStream_t stream) {
    (void)in_sizes; (void)n_in; (void)out_size; (void)d_ws; (void)ws_size;
    const float* X   = (const float*)d_in[0];
    const int*   AP  = (const int*)d_in[1];
    const int*   S   = (const int*)d_in[2];
    const int*   sec = (const int*)d_in[3];
    float* out = (float*)d_out;

    hipLaunchKernelGGL(fused_kernel, dim3(N_ / RPB), dim3(TPB), 0, stream,
                       X, AP, S, sec, out);
}